// Round 1
// baseline (870.206 us; speedup 1.0000x reference)
//
#include <hip/hip_runtime.h>
#include <math.h>

#define B 4
#define H 512
#define W 1024
#define P (H*W)            // 524288
#define NI 8
#define NSEG (NI*B)        // 32
#define NB 8192            // histogram buckets over err in [0,2]
#define INV_BW ((float)NB/2.0f)

// ws layout in 4-byte units
#define HIST_U32  (NSEG*2*NB)        // [( (n*B+b)*2 + side ) * NB + key], side 1=pos
#define OFF_CNT   (HIST_U32)         // 32 u32
#define OFF_SEMBY (OFF_CNT+32)       // 32 f
#define OFF_SEMBX (OFF_SEMBY+32)
#define OFF_SPPSY (OFF_SEMBX+32)
#define OFF_SPPSX (OFF_SPPSY+32)
#define OFF_BGCNT (OFF_SPPSX+32)     // 4 u32
#define OFF_BGSEED (OFF_BGCNT+4)     // 4 f
#define OFF_CENY  (OFF_BGSEED+4)     // 32 f
#define OFF_CENX  (OFF_CENY+32)
#define OFF_PSY   (OFF_CENX+32)
#define OFF_PSX   (OFF_PSY+32)
#define OFF_IPY   (OFF_PSX+32)
#define OFF_IPX   (OFF_IPY+32)
#define OFF_SD    (OFF_IPX+32)
#define OFF_FG    (OFF_SD+32)
#define OFF_LOV   (OFF_FG+32)
#define WS_U32_TOTAL (OFF_LOV+32)

__device__ __forceinline__ float sigmoidf_(float x){ return 1.0f/(1.0f+__expf(-x)); }

// ---------------- K1: per-instance sums + background stats ----------------
__global__ __launch_bounds__(256) void k1_reduce(const float* __restrict__ xv,
                                                 const float* __restrict__ xs,
                                                 const float* __restrict__ xseed,
                                                 const int*  __restrict__ t,
                                                 unsigned* __restrict__ ws) {
    const int b   = blockIdx.y;
    const int tid = threadIdx.x;
    __shared__ float s_semby[NI], s_sembx[NI], s_sppsy[NI], s_sppsx[NI], s_bgseed;
    __shared__ unsigned s_cnt[NI], s_bgcnt;
    if (tid < NI) { s_semby[tid]=0.f; s_sembx[tid]=0.f; s_sppsy[tid]=0.f; s_sppsx[tid]=0.f; s_cnt[tid]=0u; }
    if (tid == 0) { s_bgseed = 0.f; s_bgcnt = 0u; }
    __syncthreads();

    const float* xv_y = xv + (size_t)b*2*P;
    const float* xv_x = xv_y + P;
    const float* xs_y = xs + (size_t)b*2*P;
    const float* xs_x = xs_y + P;
    const float* sdp  = xseed + (size_t)b*P;
    const int*   tb   = t + (size_t)b*P;

    const int pixPerBlock = P / gridDim.x;              // 4096 for gridDim.x=128
    const int base = blockIdx.x * pixPerBlock;
    const int iters = pixPerBlock / (256*4);
    for (int it = 0; it < iters; ++it) {
        int p0 = base + it*1024 + tid*4;
        float4 vy = *(const float4*)(xv_y + p0);
        float4 vx = *(const float4*)(xv_x + p0);
        float4 sy = *(const float4*)(xs_y + p0);
        float4 sx = *(const float4*)(xs_x + p0);
        float4 se = *(const float4*)(sdp + p0);
        int4   tt = *(const int4*)(tb + p0);
        #pragma unroll
        for (int j = 0; j < 4; ++j) {
            int pix = p0 + j;
            float fy = (&vy.x)[j], fx = (&vx.x)[j];
            float gy = (&sy.x)[j], gx = (&sx.x)[j];
            float xsd = (&se.x)[j];
            int tv = (&tt.x)[j];
            float my = (float)(pix >> 10) * (1.0f/1024.0f);
            float mx = (float)(pix & 1023) * (1.0f/1024.0f);
            float ey = tanhf(fy) + my;
            float ex = tanhf(fx) + mx;
            if (tv == 0) {
                float s = sigmoidf_(xsd);
                atomicAdd(&s_bgseed, s*s);
                atomicAdd(&s_bgcnt, 1u);
            } else {
                int id = tv - 1;
                atomicAdd(&s_cnt[id], 1u);
                atomicAdd(&s_semby[id], ey);
                atomicAdd(&s_sembx[id], ex);
                atomicAdd(&s_sppsy[id], gy);
                atomicAdd(&s_sppsx[id], gx);
            }
        }
    }
    __syncthreads();
    if (tid < NI) {
        int seg = tid*B + b;
        atomicAdd(&ws[OFF_CNT+seg], s_cnt[tid]);
        atomicAdd((float*)&ws[OFF_SEMBY+seg], s_semby[tid]);
        atomicAdd((float*)&ws[OFF_SEMBX+seg], s_sembx[tid]);
        atomicAdd((float*)&ws[OFF_SPPSY+seg], s_sppsy[tid]);
        atomicAdd((float*)&ws[OFF_SPPSX+seg], s_sppsx[tid]);
    }
    if (tid == NI) {
        atomicAdd(&ws[OFF_BGCNT+b], s_bgcnt);
        atomicAdd((float*)&ws[OFF_BGSEED+b], s_bgseed);
    }
}

// ---------------- K2: centroids / psigma ----------------
__global__ void k2_finalize(unsigned* __restrict__ ws) {
    int i = threadIdx.x;
    if (i < NSEG) {
        unsigned c = ws[OFF_CNT+i];
        float safe = fmaxf((float)c, 1.0f);
        float ceny = ((float*)ws)[OFF_SEMBY+i] / safe;
        float cenx = ((float*)ws)[OFF_SEMBX+i] / safe;
        float ipy  = ((float*)ws)[OFF_SPPSY+i] / safe;
        float ipx  = ((float*)ws)[OFF_SPPSX+i] / safe;
        ((float*)ws)[OFF_CENY+i] = ceny;
        ((float*)ws)[OFF_CENX+i] = cenx;
        ((float*)ws)[OFF_IPY+i]  = ipy;
        ((float*)ws)[OFF_IPX+i]  = ipx;
        ((float*)ws)[OFF_PSY+i]  = expf(10.0f*ipy);
        ((float*)ws)[OFF_PSX+i]  = expf(10.0f*ipx);
    }
}

// ---------------- K3: gauss + histograms + sigma/seed-fg sums ----------------
__global__ __launch_bounds__(256) void k3_hist(const float* __restrict__ xv,
                                               const float* __restrict__ xs,
                                               const float* __restrict__ xseed,
                                               const int*  __restrict__ t,
                                               unsigned* __restrict__ ws) {
    const int b   = blockIdx.y;
    const int tid = threadIdx.x;
    __shared__ float s_ceny[NI], s_cenx[NI], s_psy[NI], s_psx[NI], s_ipy[NI], s_ipx[NI];
    __shared__ float s_sd[NI], s_fg[NI];
    if (tid < NI) {
        int seg = tid*B + b;
        s_ceny[tid] = ((float*)ws)[OFF_CENY+seg];
        s_cenx[tid] = ((float*)ws)[OFF_CENX+seg];
        s_psy[tid]  = ((float*)ws)[OFF_PSY+seg];
        s_psx[tid]  = ((float*)ws)[OFF_PSX+seg];
        s_ipy[tid]  = ((float*)ws)[OFF_IPY+seg];
        s_ipx[tid]  = ((float*)ws)[OFF_IPX+seg];
        s_sd[tid] = 0.f; s_fg[tid] = 0.f;
    }
    __syncthreads();

    // copy per-instance params to registers (avoid re-reading LDS in hot loop)
    float ceny[NI], cenx[NI], psy[NI], psx[NI];
    #pragma unroll
    for (int n = 0; n < NI; ++n) { ceny[n]=s_ceny[n]; cenx[n]=s_cenx[n]; psy[n]=s_psy[n]; psx[n]=s_psx[n]; }

    const float* xv_y = xv + (size_t)b*2*P;
    const float* xv_x = xv_y + P;
    const float* xs_y = xs + (size_t)b*2*P;
    const float* xs_x = xs_y + P;
    const float* sdp  = xseed + (size_t)b*P;
    const int*   tb   = t + (size_t)b*P;

    int p0 = (blockIdx.x*256 + tid)*4;   // gridDim.x = P/1024 = 512
    float4 vy = *(const float4*)(xv_y + p0);
    float4 vx = *(const float4*)(xv_x + p0);
    float4 sy = *(const float4*)(xs_y + p0);
    float4 sx = *(const float4*)(xs_x + p0);
    float4 se = *(const float4*)(sdp + p0);
    int4   tt = *(const int4*)(tb + p0);

    #pragma unroll
    for (int j = 0; j < 4; ++j) {
        int pix = p0 + j;
        float fy = (&vy.x)[j], fx = (&vx.x)[j];
        float gy = (&sy.x)[j], gx = (&sx.x)[j];
        float xsd = (&se.x)[j];
        int tv = (&tt.x)[j];
        float my = (float)(pix >> 10) * (1.0f/1024.0f);
        float mx = (float)(pix & 1023) * (1.0f/1024.0f);
        float ey = tanhf(fy) + my;
        float ex = tanhf(fx) + mx;

        float gown = 0.f;
        #pragma unroll
        for (int n = 0; n < NI; ++n) {
            float dy = ey - ceny[n];
            float dx = ex - cenx[n];
            float dist = psy[n]*dy*dy + psx[n]*dx*dx;
            float g = __expf(-0.5f*dist);
            bool lab = (tv == n+1);
            float err = lab ? (2.0f - 2.0f*g) : (2.0f*g);
            int key = (int)(err * INV_BW);
            key = key > (NB-1) ? (NB-1) : key;
            unsigned idx = ((unsigned)((n*B + b)*2) + (lab ? 1u : 0u)) * NB + (unsigned)key;
            atomicAdd(&ws[idx], 1u);
            if (lab) gown = g;
        }
        if (tv > 0) {
            int id = tv - 1;
            float dsy = gy - s_ipy[id];
            float dsx = gx - s_ipx[id];
            float sdv = dsy*dsy + dsx*dsx;
            float s = sigmoidf_(xsd);
            float d = s - gown;
            atomicAdd(&s_sd[id], sdv);
            atomicAdd(&s_fg[id], d*d);
        }
    }
    __syncthreads();
    if (tid < NI) {
        int seg = tid*B + b;
        atomicAdd((float*)&ws[OFF_SD+seg], s_sd[tid]);
        atomicAdd((float*)&ws[OFF_FG+seg], s_fg[tid]);
    }
}

// ---------------- K4: descending bucket scan -> lovasz per segment ----------------
__global__ __launch_bounds__(256) void k4_scan(unsigned* __restrict__ ws) {
    const int seg = blockIdx.x;
    const int tid = threadIdx.x;
    const unsigned G = ws[OFF_CNT+seg];
    __shared__ unsigned sp[256], sn[256];
    __shared__ unsigned off_p, off_n;
    __shared__ double sred[256];
    if (tid == 0) { off_p = 0u; off_n = 0u; }
    __syncthreads();
    double acc = 0.0;
    const unsigned* hp = ws + ((size_t)seg*2 + 1)*NB;
    const unsigned* hn = ws + ((size_t)seg*2 + 0)*NB;
    if (G > 0) {
        const double dG = (double)G;
        for (int c = 0; c < NB/256; ++c) {
            int key = NB-1 - (c*256 + tid);
            unsigned cp = hp[key], cn = hn[key];
            sp[tid] = cp; sn[tid] = cn;
            __syncthreads();
            for (int d = 1; d < 256; d <<= 1) {
                unsigned ap = 0u, an = 0u;
                if (tid >= d) { ap = sp[tid-d]; an = sn[tid-d]; }
                __syncthreads();
                sp[tid] += ap; sn[tid] += an;
                __syncthreads();
            }
            unsigned ip = sp[tid], inn = sn[tid];
            unsigned ep = off_p + ip - cp;
            unsigned en = off_n + inn - cn;
            double jb = 1.0 - (dG - (double)ep) / (dG + (double)en);
            double ja = 1.0 - (dG - (double)(ep+cp)) / (dG + (double)(en+cn));
            double ek = ((double)key + 0.5) * (2.0/(double)NB);
            acc += ek * (ja - jb);
            __syncthreads();
            if (tid == 255) { off_p += sp[255]; off_n += sn[255]; }
            __syncthreads();
        }
    }
    sred[tid] = acc;
    __syncthreads();
    for (int d = 128; d > 0; d >>= 1) {
        if (tid < d) sred[tid] += sred[tid+d];
        __syncthreads();
    }
    if (tid == 0) ((float*)ws)[OFF_LOV+seg] = (float)sred[0];
}

// ---------------- K5: combine to scalar ----------------
__global__ void k5_final(unsigned* __restrict__ ws, float* __restrict__ out) {
    if (threadIdx.x == 0 && blockIdx.x == 0) {
        float lovz = 0.f, sig = 0.f, seedl = 0.f;
        for (int b = 0; b < B; ++b) {
            int npc = 0; float lsum = 0.f, ssum = 0.f, fsum = 0.f;
            for (int n = 0; n < NI; ++n) {
                int seg = n*B + b;
                unsigned c = ws[OFF_CNT+seg];
                if (c > 0) {
                    npc++;
                    float safe = (float)c;
                    lsum += ((float*)ws)[OFF_LOV+seg];
                    ssum += ((float*)ws)[OFF_SD+seg] / safe;
                    fsum += ((float*)ws)[OFF_FG+seg] / safe;
                }
            }
            float npf = fmaxf((float)npc, 1.0f);
            lovz += lsum / npf;
            sig  += ssum / npf;
            unsigned bgc = ws[OFF_BGCNT+b];
            float bgl = ((float*)ws)[OFF_BGSEED+b] / fmaxf((float)bgc, 1.0f);
            seedl += (bgl + fsum) / (1.0f + (float)npc);
        }
        out[0] = (lovz + sig + seedl) * (1.0f/(float)B);
    }
}

extern "C" void kernel_launch(void* const* d_in, const int* in_sizes, int n_in,
                              void* d_out, int out_size, void* d_ws, size_t ws_size,
                              hipStream_t stream) {
    (void)in_sizes; (void)n_in; (void)out_size; (void)ws_size;
    const float* xv  = (const float*)d_in[0];
    const float* xs  = (const float*)d_in[1];
    const float* xsd = (const float*)d_in[2];
    const int*   t   = (const int*)d_in[3];
    unsigned* ws = (unsigned*)d_ws;
    float* out = (float*)d_out;

    hipMemsetAsync(d_ws, 0, (size_t)WS_U32_TOTAL*4, stream);

    dim3 g1(128, B);
    k1_reduce<<<g1, 256, 0, stream>>>(xv, xs, xsd, t, ws);
    k2_finalize<<<1, 64, 0, stream>>>(ws);
    dim3 g3(P/1024, B);
    k3_hist<<<g3, 256, 0, stream>>>(xv, xs, xsd, t, ws);
    k4_scan<<<NSEG, 256, 0, stream>>>(ws);
    k5_final<<<1, 64, 0, stream>>>(ws, out);
}

// Round 2
// 293.329 us; speedup vs baseline: 2.9667x; 2.9667x over previous
//
#include <hip/hip_runtime.h>
#include <math.h>

#define B 4
#define H 512
#define W 1024
#define P (H*W)            // 524288
#define NI 8
#define NSEG (NI*B)        // 32
#define NB 8192            // histogram buckets over err in [0,2]
#define INV_BW ((float)NB/2.0f)
#define NSTRIP 16
#define STRIP_PX (P/NSTRIP) // 32768

// ---- ws layout (float/u32 units) ----
#define A_CNT    0          // 32 f  (counts, exact in f32)
#define A_SEY    32         // 32 f
#define A_SEX    64
#define A_SGY    96
#define A_SGX    128
#define A_SQ     160        // sum of gy^2+gx^2
#define A_BGCNT  192        // 4 f
#define A_BGSEED 196        // 4 f
#define D_CENY   200
#define D_CENX   232
#define D_PSY    264
#define D_PSX    296
#define D_SL     328        // sigma loss per seg (already mean-adjusted)
#define D_FG     360        // raw fg seed sum per seg
#define D_LOV    392
#define ACC_U32  512        // memset region (2 KB)
#define OFF_HIST 512        // NSTRIP*NSEG*NB u32 = 16 MB, fully overwritten

__device__ __forceinline__ float fast_tanh(float x) {
    float e = __expf(2.0f * x);
    return 1.0f - 2.0f / (e + 1.0f);   // handles overflow: e=inf -> 1
}
__device__ __forceinline__ float fast_sigmoid(float x) {
    return 1.0f / (1.0f + __expf(-x));
}
__device__ __forceinline__ float wave_red(float v) {
    #pragma unroll
    for (int d = 32; d > 0; d >>= 1) v += __shfl_down(v, d);
    return v;
}

// ---------------- K1: per-instance sums + background stats (register-private) ----
__global__ __launch_bounds__(256) void k1_reduce(const float* __restrict__ xv,
                                                 const float* __restrict__ xs,
                                                 const float* __restrict__ xseed,
                                                 const int*  __restrict__ t,
                                                 float* __restrict__ wsf) {
    const int b   = blockIdx.y;
    const int tid = threadIdx.x;
    const float* xv_y = xv + (size_t)b*2*P;
    const float* xv_x = xv_y + P;
    const float* xs_y = xs + (size_t)b*2*P;
    const float* xs_x = xs_y + P;
    const float* sdp  = xseed + (size_t)b*P;
    const int*   tb   = t + (size_t)b*P;

    float cnt[NI], sey[NI], sex[NI], sgy[NI], sgx[NI], sq[NI];
    #pragma unroll
    for (int n = 0; n < NI; ++n) { cnt[n]=0.f; sey[n]=0.f; sex[n]=0.f; sgy[n]=0.f; sgx[n]=0.f; sq[n]=0.f; }
    float bgc = 0.f, bgs = 0.f;

    const int base = blockIdx.x * (P / gridDim.x);   // gridDim.x = 64 -> 8192 px/block
    for (int it = 0; it < 8; ++it) {
        int p0 = base + it*1024 + tid*4;
        float4 vy = *(const float4*)(xv_y + p0);
        float4 vx = *(const float4*)(xv_x + p0);
        float4 sy = *(const float4*)(xs_y + p0);
        float4 sx = *(const float4*)(xs_x + p0);
        float4 se = *(const float4*)(sdp + p0);
        int4   tt = *(const int4*)(tb + p0);
        #pragma unroll
        for (int j = 0; j < 4; ++j) {
            int pix = p0 + j;
            float ey = fast_tanh((&vy.x)[j]) + (float)(pix >> 10) * (1.0f/1024.0f);
            float ex = fast_tanh((&vx.x)[j]) + (float)(pix & 1023) * (1.0f/1024.0f);
            float gy = (&sy.x)[j], gx = (&sx.x)[j];
            int tv = (&tt.x)[j];
            if (tv == 0) {
                float s = fast_sigmoid((&se.x)[j]);
                bgc += 1.f; bgs += s*s;
            }
            float q = gy*gy + gx*gx;
            #pragma unroll
            for (int n = 0; n < NI; ++n) {
                float m = (tv == n+1) ? 1.0f : 0.0f;
                cnt[n] += m; sey[n] += m*ey; sex[n] += m*ex;
                sgy[n] += m*gy; sgx[n] += m*gx; sq[n] += m*q;
            }
        }
    }
    // wave reduce + global atomic flush (lane 0 of each wave)
    const bool l0 = (tid & 63) == 0;
    #pragma unroll
    for (int n = 0; n < NI; ++n) {
        int seg = n*B + b;
        float v;
        v = wave_red(cnt[n]); if (l0 && v != 0.f) atomicAdd(&wsf[A_CNT+seg], v);
        v = wave_red(sey[n]); if (l0) atomicAdd(&wsf[A_SEY+seg], v);
        v = wave_red(sex[n]); if (l0) atomicAdd(&wsf[A_SEX+seg], v);
        v = wave_red(sgy[n]); if (l0) atomicAdd(&wsf[A_SGY+seg], v);
        v = wave_red(sgx[n]); if (l0) atomicAdd(&wsf[A_SGX+seg], v);
        v = wave_red(sq[n]);  if (l0) atomicAdd(&wsf[A_SQ+seg],  v);
    }
    float v;
    v = wave_red(bgc); if (l0) atomicAdd(&wsf[A_BGCNT+b], v);
    v = wave_red(bgs); if (l0) atomicAdd(&wsf[A_BGSEED+b], v);
}

// ---------------- K2: centroids / psigma / sigma loss ----------------
__global__ void k2_finalize(float* __restrict__ wsf) {
    int i = threadIdx.x;
    if (i < NSEG) {
        float c = wsf[A_CNT+i];
        float safe = fmaxf(c, 1.0f);
        float ceny = wsf[A_SEY+i] / safe;
        float cenx = wsf[A_SEX+i] / safe;
        float ipy  = wsf[A_SGY+i] / safe;
        float ipx  = wsf[A_SGX+i] / safe;
        wsf[D_CENY+i] = ceny;
        wsf[D_CENX+i] = cenx;
        wsf[D_PSY+i]  = expf(10.0f*ipy);
        wsf[D_PSX+i]  = expf(10.0f*ipx);
        wsf[D_SL+i]   = wsf[A_SQ+i] / safe - (ipy*ipy + ipx*ipx);
    }
}

// ---------------- K3: LDS-private histogram per (strip, n, b) ----------------
__global__ __launch_bounds__(256) void k3_hist(const float* __restrict__ xv,
                                               const float* __restrict__ xseed,
                                               const int*  __restrict__ t,
                                               float* __restrict__ wsf,
                                               unsigned* __restrict__ hist_g) {
    const int strip = blockIdx.x;
    const int n     = blockIdx.y;
    const int b     = blockIdx.z;
    const int tid   = threadIdx.x;
    const int seg   = n*B + b;

    __shared__ unsigned hist[NB];   // 32 KB: pos<<16 | neg (u16 each, strip<=32768)
    for (int i = tid; i < NB; i += 256) hist[i] = 0u;

    const float ceny = wsf[D_CENY+seg];
    const float cenx = wsf[D_CENX+seg];
    const float psy  = wsf[D_PSY+seg];
    const float psx  = wsf[D_PSX+seg];
    __syncthreads();

    const float* xv_y = xv + (size_t)b*2*P;
    const float* xv_x = xv_y + P;
    const float* sdp  = xseed + (size_t)b*P;
    const int*   tb   = t + (size_t)b*P;
    const int base = strip * STRIP_PX;

    float fg_acc = 0.f;
    for (int it = 0; it < STRIP_PX/1024; ++it) {   // 32 iters
        int p0 = base + it*1024 + tid*4;
        float4 vy = *(const float4*)(xv_y + p0);
        float4 vx = *(const float4*)(xv_x + p0);
        float4 se = *(const float4*)(sdp + p0);
        int4   tt = *(const int4*)(tb + p0);
        #pragma unroll
        for (int j = 0; j < 4; ++j) {
            int pix = p0 + j;
            float ey = fast_tanh((&vy.x)[j]) + (float)(pix >> 10) * (1.0f/1024.0f);
            float ex = fast_tanh((&vx.x)[j]) + (float)(pix & 1023) * (1.0f/1024.0f);
            int tv = (&tt.x)[j];
            float dy = ey - ceny, dx = ex - cenx;
            float g = __expf(-0.5f * (psy*dy*dy + psx*dx*dx));
            bool lab = (tv == n+1);
            float err = lab ? (2.0f - 2.0f*g) : (2.0f*g);
            int key = (int)(err * INV_BW);
            key = key > (NB-1) ? (NB-1) : key;
            atomicAdd(&hist[key], lab ? 0x10000u : 1u);
            if (lab) {
                float s = fast_sigmoid((&se.x)[j]);
                float d = s - g;
                fg_acc += d*d;
            }
        }
    }
    __syncthreads();
    // plain coalesced flush — no atomics
    unsigned* dst = hist_g + (((size_t)strip*NI + n)*B + b)*NB;
    for (int i = tid; i < NB; i += 256) dst[i] = hist[i];
    float v = wave_red(fg_acc);
    if ((tid & 63) == 0) atomicAdd(&wsf[D_FG+seg], v);
}

// ---------------- K4: descending bucket scan (shuffle-based) ----------------
__global__ __launch_bounds__(256) void k4_scan(const unsigned* __restrict__ hist_g,
                                               float* __restrict__ wsf) {
    const int seg = blockIdx.x;
    const int n = seg / B, b = seg % B;
    const int tid = threadIdx.x;
    const int lane = tid & 63, wid = tid >> 6;
    const float Gf = wsf[A_CNT+seg];
    if (Gf < 0.5f) { if (tid == 0) wsf[D_LOV+seg] = 0.f; return; }
    const double dG = (double)Gf;

    __shared__ unsigned swp[4], swn[4];
    __shared__ double sdd[4];
    double accv = 0.0;
    unsigned offp = 0u, offn = 0u;

    for (int c = 0; c < NB/256; ++c) {
        int key = NB-1 - (c*256 + tid);
        unsigned pos = 0u, neg = 0u;
        #pragma unroll
        for (int s = 0; s < NSTRIP; ++s) {
            unsigned v = hist_g[(((size_t)s*NI + n)*B + b)*NB + key];
            pos += v >> 16; neg += v & 0xffffu;
        }
        unsigned ip = pos, in_ = neg;
        #pragma unroll
        for (int d = 1; d < 64; d <<= 1) {
            unsigned vp = __shfl_up(ip, d);
            unsigned vn = __shfl_up(in_, d);
            if (lane >= d) { ip += vp; in_ += vn; }
        }
        if (lane == 63) { swp[wid] = ip; swn[wid] = in_; }
        __syncthreads();
        unsigned wpp = 0u, wpn = 0u, totp = 0u, totn = 0u;
        #pragma unroll
        for (int w = 0; w < 4; ++w) {
            unsigned tp = swp[w], tn = swn[w];
            if (w < wid) { wpp += tp; wpn += tn; }
            totp += tp; totn += tn;
        }
        if (pos | neg) {
            unsigned ep_i = offp + wpp + ip;      // inclusive cum (desc order)
            unsigned en_i = offn + wpn + in_;
            unsigned ep = ep_i - pos, en = en_i - neg;
            double jb = 1.0 - (dG - (double)ep)   / (dG + (double)en);
            double ja = 1.0 - (dG - (double)ep_i) / (dG + (double)en_i);
            accv += (((double)key + 0.5) * (2.0/(double)NB)) * (ja - jb);
        }
        offp += totp; offn += totn;
        __syncthreads();
    }
    #pragma unroll
    for (int d = 32; d > 0; d >>= 1) accv += __shfl_down(accv, d);
    if (lane == 0) sdd[wid] = accv;
    __syncthreads();
    if (tid == 0) wsf[D_LOV+seg] = (float)(sdd[0]+sdd[1]+sdd[2]+sdd[3]);
}

// ---------------- K5: combine to scalar ----------------
__global__ void k5_final(const float* __restrict__ wsf, float* __restrict__ out) {
    if (threadIdx.x == 0 && blockIdx.x == 0) {
        float lovz = 0.f, sig = 0.f, seedl = 0.f;
        for (int b = 0; b < B; ++b) {
            int npc = 0; float lsum = 0.f, ssum = 0.f, fsum = 0.f;
            for (int n = 0; n < NI; ++n) {
                int seg = n*B + b;
                float c = wsf[A_CNT+seg];
                if (c > 0.5f) {
                    npc++;
                    lsum += wsf[D_LOV+seg];
                    ssum += wsf[D_SL+seg];
                    fsum += wsf[D_FG+seg] / c;
                }
            }
            float npf = fmaxf((float)npc, 1.0f);
            lovz += lsum / npf;
            sig  += ssum / npf;
            float bgl = wsf[A_BGSEED+b] / fmaxf(wsf[A_BGCNT+b], 1.0f);
            seedl += (bgl + fsum) / (1.0f + (float)npc);
        }
        out[0] = (lovz + sig + seedl) * (1.0f/(float)B);
    }
}

extern "C" void kernel_launch(void* const* d_in, const int* in_sizes, int n_in,
                              void* d_out, int out_size, void* d_ws, size_t ws_size,
                              hipStream_t stream) {
    (void)in_sizes; (void)n_in; (void)out_size; (void)ws_size;
    const float* xv  = (const float*)d_in[0];
    const float* xs  = (const float*)d_in[1];
    const float* xsd = (const float*)d_in[2];
    const int*   t   = (const int*)d_in[3];
    float* wsf = (float*)d_ws;
    unsigned* hist_g = (unsigned*)d_ws + OFF_HIST;
    float* out = (float*)d_out;

    hipMemsetAsync(d_ws, 0, (size_t)ACC_U32*4, stream);

    dim3 g1(64, B);
    k1_reduce<<<g1, 256, 0, stream>>>(xv, xs, xsd, t, wsf);
    k2_finalize<<<1, 64, 0, stream>>>(wsf);
    dim3 g3(NSTRIP, NI, B);
    k3_hist<<<g3, 256, 0, stream>>>(xv, xsd, t, wsf, hist_g);
    k4_scan<<<NSEG, 256, 0, stream>>>(hist_g, wsf);
    k5_final<<<1, 64, 0, stream>>>(wsf, out);
}

// Round 3
// 165.250 us; speedup vs baseline: 5.2660x; 1.7751x over previous
//
#include <hip/hip_runtime.h>
#include <math.h>

#define B 4
#define H 512
#define W 1024
#define P (H*W)            // 524288
#define NI 8
#define NSEG (NI*B)        // 32
#define NB 1024            // histogram buckets over err in [0,2]
#define INV_BW ((float)NB/2.0f)
#define NSTRIP 128
#define STRIP_PX (P/NSTRIP) // 4096

// ---- ws layout (float/u32 units) ----
#define A_CNT    0          // 32 f  (counts, exact in f32)
#define A_SEY    32         // 32 f
#define A_SEX    64
#define A_SGY    96
#define A_SGX    128
#define A_SQ     160        // sum of gy^2+gx^2
#define A_BGCNT  192        // 4 f
#define A_BGSEED 196        // 4 f
#define D_CENY   200
#define D_CENX   232
#define D_PSY    264
#define D_PSX    296
#define D_SL     328        // sigma loss per seg
#define D_FG     360        // raw fg seed sum per seg
#define D_LOV    392
#define ACC_U32  512        // memset region (2 KB)
#define OFF_HIST 512        // [seg][strip][key] : NSEG*NSTRIP*NB u32 = 16 MB

__device__ __forceinline__ float fast_tanh(float x) {
    float e = __expf(2.0f * x);
    return 1.0f - 2.0f / (e + 1.0f);
}
__device__ __forceinline__ float fast_sigmoid(float x) {
    return 1.0f / (1.0f + __expf(-x));
}
__device__ __forceinline__ float wave_red(float v) {
    #pragma unroll
    for (int d = 32; d > 0; d >>= 1) v += __shfl_down(v, d);
    return v;
}

// ---------------- K1: per-instance sums + background stats ----------------
__global__ __launch_bounds__(256) void k1_reduce(const float* __restrict__ xv,
                                                 const float* __restrict__ xs,
                                                 const float* __restrict__ xseed,
                                                 const int*  __restrict__ t,
                                                 float* __restrict__ wsf) {
    const int b   = blockIdx.y;
    const int tid = threadIdx.x;
    __shared__ float sacc[50];
    if (tid < 50) sacc[tid] = 0.f;
    __syncthreads();

    const float* xv_y = xv + (size_t)b*2*P;
    const float* xv_x = xv_y + P;
    const float* xs_y = xs + (size_t)b*2*P;
    const float* xs_x = xs_y + P;
    const float* sdp  = xseed + (size_t)b*P;
    const int*   tb   = t + (size_t)b*P;

    float cnt[NI], sey[NI], sex[NI], sgy[NI], sgx[NI], sq[NI];
    #pragma unroll
    for (int n = 0; n < NI; ++n) { cnt[n]=0.f; sey[n]=0.f; sex[n]=0.f; sgy[n]=0.f; sgx[n]=0.f; sq[n]=0.f; }
    float bgc = 0.f, bgs = 0.f;

    const int base = blockIdx.x * 2048;     // gridDim.x = 256
    #pragma unroll
    for (int it = 0; it < 2; ++it) {
        int p0 = base + it*1024 + tid*4;
        float4 vy = *(const float4*)(xv_y + p0);
        float4 vx = *(const float4*)(xv_x + p0);
        float4 sy = *(const float4*)(xs_y + p0);
        float4 sx = *(const float4*)(xs_x + p0);
        float4 se = *(const float4*)(sdp + p0);
        int4   tt = *(const int4*)(tb + p0);
        #pragma unroll
        for (int j = 0; j < 4; ++j) {
            int pix = p0 + j;
            float ey = fast_tanh((&vy.x)[j]) + (float)(pix >> 10) * (1.0f/1024.0f);
            float ex = fast_tanh((&vx.x)[j]) + (float)(pix & 1023) * (1.0f/1024.0f);
            float gy = (&sy.x)[j], gx = (&sx.x)[j];
            int tv = (&tt.x)[j];
            if (tv == 0) {
                float s = fast_sigmoid((&se.x)[j]);
                bgc += 1.f; bgs += s*s;
            }
            float q = gy*gy + gx*gx;
            #pragma unroll
            for (int n = 0; n < NI; ++n) {
                float m = (tv == n+1) ? 1.0f : 0.0f;
                cnt[n] += m; sey[n] += m*ey; sex[n] += m*ex;
                sgy[n] += m*gy; sgx[n] += m*gx; sq[n] += m*q;
            }
        }
    }
    const bool l0 = (tid & 63) == 0;
    #pragma unroll
    for (int n = 0; n < NI; ++n) {
        float v;
        v = wave_red(cnt[n]); if (l0) atomicAdd(&sacc[n*6+0], v);
        v = wave_red(sey[n]); if (l0) atomicAdd(&sacc[n*6+1], v);
        v = wave_red(sex[n]); if (l0) atomicAdd(&sacc[n*6+2], v);
        v = wave_red(sgy[n]); if (l0) atomicAdd(&sacc[n*6+3], v);
        v = wave_red(sgx[n]); if (l0) atomicAdd(&sacc[n*6+4], v);
        v = wave_red(sq[n]);  if (l0) atomicAdd(&sacc[n*6+5], v);
    }
    float v;
    v = wave_red(bgc); if (l0) atomicAdd(&sacc[48], v);
    v = wave_red(bgs); if (l0) atomicAdd(&sacc[49], v);
    __syncthreads();
    if (tid < 48) {
        int n = tid / 6, q = tid - n*6;
        atomicAdd(&wsf[q*32 + n*B + b], sacc[tid]);
    } else if (tid == 48) {
        atomicAdd(&wsf[A_BGCNT+b], sacc[48]);
    } else if (tid == 49) {
        atomicAdd(&wsf[A_BGSEED+b], sacc[49]);
    }
}

// ---------------- K2: centroids / psigma / sigma loss ----------------
__global__ void k2_finalize(float* __restrict__ wsf) {
    int i = threadIdx.x;
    if (i < NSEG) {
        float c = wsf[A_CNT+i];
        float safe = fmaxf(c, 1.0f);
        float ceny = wsf[A_SEY+i] / safe;
        float cenx = wsf[A_SEX+i] / safe;
        float ipy  = wsf[A_SGY+i] / safe;
        float ipx  = wsf[A_SGX+i] / safe;
        wsf[D_CENY+i] = ceny;
        wsf[D_CENX+i] = cenx;
        wsf[D_PSY+i]  = expf(10.0f*ipy);
        wsf[D_PSX+i]  = expf(10.0f*ipx);
        wsf[D_SL+i]   = wsf[A_SQ+i] / safe - (ipy*ipy + ipx*ipx);
    }
}

// ---------------- K3: all-instance LDS histograms per (strip, b) ----------------
__global__ __launch_bounds__(512) void k3_hist(const float* __restrict__ xv,
                                               const float* __restrict__ xseed,
                                               const int*  __restrict__ t,
                                               float* __restrict__ wsf,
                                               unsigned* __restrict__ hist_g) {
    const int strip = blockIdx.x;
    const int b     = blockIdx.y;
    const int tid   = threadIdx.x;

    __shared__ unsigned hist[NI*NB];   // 32 KB: pos<<16 | neg (u16 each, strip=4096 px)
    for (int i = tid; i < NI*NB; i += 512) hist[i] = 0u;

    float ceny[NI], cenx[NI], psy[NI], psx[NI], fgn[NI];
    #pragma unroll
    for (int n = 0; n < NI; ++n) {
        int seg = n*B + b;
        ceny[n] = wsf[D_CENY+seg];
        cenx[n] = wsf[D_CENX+seg];
        psy[n]  = wsf[D_PSY+seg];
        psx[n]  = wsf[D_PSX+seg];
        fgn[n]  = 0.f;
    }
    __syncthreads();

    const float* xv_y = xv + (size_t)b*2*P;
    const float* xv_x = xv_y + P;
    const float* sdp  = xseed + (size_t)b*P;
    const int*   tb   = t + (size_t)b*P;
    const int base = strip * STRIP_PX;

    #pragma unroll
    for (int it = 0; it < STRIP_PX/2048; ++it) {   // 2 iters
        int p0 = base + it*2048 + tid*4;
        float4 vy = *(const float4*)(xv_y + p0);
        float4 vx = *(const float4*)(xv_x + p0);
        float4 se = *(const float4*)(sdp + p0);
        int4   tt = *(const int4*)(tb + p0);
        #pragma unroll
        for (int j = 0; j < 4; ++j) {
            int pix = p0 + j;
            float ey = fast_tanh((&vy.x)[j]) + (float)(pix >> 10) * (1.0f/1024.0f);
            float ex = fast_tanh((&vx.x)[j]) + (float)(pix & 1023) * (1.0f/1024.0f);
            int tv = (&tt.x)[j];
            float gown = 0.f;
            #pragma unroll
            for (int n = 0; n < NI; ++n) {
                float dy = ey - ceny[n], dx = ex - cenx[n];
                float g = __expf(-0.5f * (psy[n]*dy*dy + psx[n]*dx*dx));
                bool lab = (tv == n+1);
                float err = lab ? (2.0f - 2.0f*g) : (2.0f*g);
                int key = (int)(err * INV_BW);
                key = key > (NB-1) ? (NB-1) : key;
                atomicAdd(&hist[n*NB + key], lab ? 0x10000u : 1u);
                if (lab) gown = g;
            }
            if (tv > 0) {
                float s = fast_sigmoid((&se.x)[j]);
                float d = s - gown;
                float dd = d*d;
                #pragma unroll
                for (int n = 0; n < NI; ++n) fgn[n] += (tv == n+1) ? dd : 0.f;
            }
        }
    }
    __syncthreads();
    // plain coalesced flush — no atomics
    for (int i = tid; i < NI*NB; i += 512) {
        int n = i >> 10, key = i & (NB-1);
        int seg = n*B + b;
        hist_g[((size_t)(seg*NSTRIP + strip))*NB + key] = hist[i];
    }
    __shared__ float sfg[NI];
    if (tid < NI) sfg[tid] = 0.f;
    __syncthreads();
    const bool l0 = (tid & 63) == 0;
    #pragma unroll
    for (int n = 0; n < NI; ++n) {
        float v = wave_red(fgn[n]);
        if (l0 && v != 0.f) atomicAdd(&sfg[n], v);
    }
    __syncthreads();
    if (tid < NI) {
        float v = sfg[tid];
        if (v != 0.f) atomicAdd(&wsf[D_FG + tid*B + b], v);
    }
}

// ---------------- K4a: fold strips -> combined per-seg histograms ----------------
__global__ __launch_bounds__(256) void k4a_fold(unsigned* __restrict__ hist_g) {
    const int seg = blockIdx.x >> 2;                 // NB/256 = 4 key-blocks
    const int key = (blockIdx.x & 3)*256 + threadIdx.x;
    const unsigned* src = hist_g + (size_t)seg*NSTRIP*NB + key;
    unsigned pos = 0u, neg = 0u;
    for (int s = 0; s < NSTRIP; ++s) {
        unsigned v = src[(size_t)s*NB];
        pos += v >> 16; neg += v & 0xffffu;
    }
    // overwrite strip-0/strip-1 slots of this seg (this thread already read them)
    hist_g[((size_t)seg*NSTRIP + 0)*NB + key] = pos;
    hist_g[((size_t)seg*NSTRIP + 1)*NB + key] = neg;
}

// ---------------- K4b: descending bucket scan -> lovasz ----------------
__global__ __launch_bounds__(256) void k4b_scan(const unsigned* __restrict__ hist_g,
                                                float* __restrict__ wsf) {
    const int seg = blockIdx.x;
    const int tid = threadIdx.x;
    const int lane = tid & 63, wid = tid >> 6;
    const float Gf = wsf[A_CNT+seg];
    if (Gf < 0.5f) { if (tid == 0) wsf[D_LOV+seg] = 0.f; return; }
    const double dG = (double)Gf;

    const unsigned* hp = hist_g + ((size_t)seg*NSTRIP + 0)*NB;
    const unsigned* hn = hist_g + ((size_t)seg*NSTRIP + 1)*NB;

    __shared__ unsigned swp[4], swn[4];
    __shared__ double sdd[4];
    double accv = 0.0;
    unsigned offp = 0u, offn = 0u;

    #pragma unroll
    for (int c = 0; c < NB/256; ++c) {   // 4 chunks
        int key = NB-1 - (c*256 + tid);
        unsigned pos = hp[key], neg = hn[key];
        unsigned ip = pos, in_ = neg;
        #pragma unroll
        for (int d = 1; d < 64; d <<= 1) {
            unsigned vp = __shfl_up(ip, d);
            unsigned vn = __shfl_up(in_, d);
            if (lane >= d) { ip += vp; in_ += vn; }
        }
        if (lane == 63) { swp[wid] = ip; swn[wid] = in_; }
        __syncthreads();
        unsigned wpp = 0u, wpn = 0u, totp = 0u, totn = 0u;
        #pragma unroll
        for (int w = 0; w < 4; ++w) {
            unsigned tp = swp[w], tn = swn[w];
            if (w < wid) { wpp += tp; wpn += tn; }
            totp += tp; totn += tn;
        }
        if (pos | neg) {
            unsigned ep_i = offp + wpp + ip;
            unsigned en_i = offn + wpn + in_;
            unsigned ep = ep_i - pos, en = en_i - neg;
            double jb = 1.0 - (dG - (double)ep)   / (dG + (double)en);
            double ja = 1.0 - (dG - (double)ep_i) / (dG + (double)en_i);
            accv += (((double)key + 0.5) * (2.0/(double)NB)) * (ja - jb);
        }
        offp += totp; offn += totn;
        __syncthreads();
    }
    #pragma unroll
    for (int d = 32; d > 0; d >>= 1) accv += __shfl_down(accv, d);
    if (lane == 0) sdd[wid] = accv;
    __syncthreads();
    if (tid == 0) wsf[D_LOV+seg] = (float)(sdd[0]+sdd[1]+sdd[2]+sdd[3]);
}

// ---------------- K5: combine to scalar ----------------
__global__ void k5_final(const float* __restrict__ wsf, float* __restrict__ out) {
    if (threadIdx.x == 0 && blockIdx.x == 0) {
        float lovz = 0.f, sig = 0.f, seedl = 0.f;
        for (int b = 0; b < B; ++b) {
            int npc = 0; float lsum = 0.f, ssum = 0.f, fsum = 0.f;
            for (int n = 0; n < NI; ++n) {
                int seg = n*B + b;
                float c = wsf[A_CNT+seg];
                if (c > 0.5f) {
                    npc++;
                    lsum += wsf[D_LOV+seg];
                    ssum += wsf[D_SL+seg];
                    fsum += wsf[D_FG+seg] / c;
                }
            }
            float npf = fmaxf((float)npc, 1.0f);
            lovz += lsum / npf;
            sig  += ssum / npf;
            float bgl = wsf[A_BGSEED+b] / fmaxf(wsf[A_BGCNT+b], 1.0f);
            seedl += (bgl + fsum) / (1.0f + (float)npc);
        }
        out[0] = (lovz + sig + seedl) * (1.0f/(float)B);
    }
}

extern "C" void kernel_launch(void* const* d_in, const int* in_sizes, int n_in,
                              void* d_out, int out_size, void* d_ws, size_t ws_size,
                              hipStream_t stream) {
    (void)in_sizes; (void)n_in; (void)out_size; (void)ws_size;
    const float* xv  = (const float*)d_in[0];
    const float* xs  = (const float*)d_in[1];
    const float* xsd = (const float*)d_in[2];
    const int*   t   = (const int*)d_in[3];
    float* wsf = (float*)d_ws;
    unsigned* hist_g = (unsigned*)d_ws + OFF_HIST;
    float* out = (float*)d_out;

    hipMemsetAsync(d_ws, 0, (size_t)ACC_U32*4, stream);

    dim3 g1(256, B);
    k1_reduce<<<g1, 256, 0, stream>>>(xv, xs, xsd, t, wsf);
    k2_finalize<<<1, 64, 0, stream>>>(wsf);
    dim3 g3(NSTRIP, B);
    k3_hist<<<g3, 512, 0, stream>>>(xv, xsd, t, wsf, hist_g);
    k4a_fold<<<NSEG*(NB/256), 256, 0, stream>>>(hist_g);
    k4b_scan<<<NSEG, 256, 0, stream>>>(hist_g, wsf);
    k5_final<<<1, 64, 0, stream>>>(wsf, out);
}

// Round 4
// 139.624 us; speedup vs baseline: 6.2325x; 1.1835x over previous
//
#include <hip/hip_runtime.h>
#include <math.h>

#define B 4
#define H 512
#define W 1024
#define P (H*W)            // 524288
#define NI 8
#define NSEG 32            // seg = n*B + b
#define NB 1024            // histogram buckets over err in [0,2]
#define INV_BW ((float)NB/2.0f)
#define NSTRIP 128
#define STRIP_PX (P/NSTRIP) // 4096
#define K1B 512             // k1 blocks per batch
#define K1PX (P/K1B)        // 1024 px per k1 block

// ---- ws layout (4-byte units) ----
#define D_CENY 0
#define D_CENX 32
#define D_PSY  64
#define D_PSX  96
#define D_CNT  128
#define D_SL   160
#define D_BGL  192          // 4
#define OFF_FGP 256         // NI*512 floats = 16 KB
#define OFF_HIST (256 + NI*512)              // u32: NSEG*NSTRIP*NB = 16 MB
#define OFF_PK1  OFF_HIST   // pk1 (2048*64 floats = 512 KB) overlaps hist:
                            // k1 writes pk1 -> k2 consumes -> k3 overwrites hist. Safe.

__device__ __forceinline__ float fast_tanh(float x) {
    float e = __expf(2.0f * x);
    return 1.0f - 2.0f / (e + 1.0f);
}
__device__ __forceinline__ float fast_sigmoid(float x) {
    return 1.0f / (1.0f + __expf(-x));
}

// DPP wave64 sum-reduction (rocPRIM sequence): total lands in lane 63.
template<int CTRL, int RM>
__device__ __forceinline__ float dpp_add(float x) {
    int y = __builtin_amdgcn_update_dpp(0, __float_as_int(x), CTRL, RM, 0xF, true);
    return x + __int_as_float(y);
}
__device__ __forceinline__ float wred(float x) {
    x = dpp_add<0x111, 0xF>(x);   // row_shr:1
    x = dpp_add<0x112, 0xF>(x);   // row_shr:2
    x = dpp_add<0x114, 0xF>(x);   // row_shr:4
    x = dpp_add<0x118, 0xF>(x);   // row_shr:8
    x = dpp_add<0x142, 0xA>(x);   // row_bcast:15 -> rows 1,3
    x = dpp_add<0x143, 0xC>(x);   // row_bcast:31 -> rows 2,3
    return x;                     // lane 63 = wave total
}

// ---------------- K1: per-block partial sums (no global atomics) ----------------
__global__ __launch_bounds__(256) void k1_stats(const float* __restrict__ xv,
                                                const float* __restrict__ xs,
                                                const float* __restrict__ xseed,
                                                const int*  __restrict__ t,
                                                float* __restrict__ pk1) {
    const int b = blockIdx.y, bx = blockIdx.x, tid = threadIdx.x;
    const int lane = tid & 63, wid = tid >> 6;
    const float* xv_y = xv + (size_t)b*2*P;
    const float* xv_x = xv_y + P;
    const float* xs_y = xs + (size_t)b*2*P;
    const float* xs_x = xs_y + P;
    const float* sdp  = xseed + (size_t)b*P;
    const int*   tb   = t + (size_t)b*P;

    float cnt[NI], sey[NI], sex[NI], sgy[NI], sgx[NI], sq[NI];
    #pragma unroll
    for (int n = 0; n < NI; ++n) { cnt[n]=0.f; sey[n]=0.f; sex[n]=0.f; sgy[n]=0.f; sgx[n]=0.f; sq[n]=0.f; }
    float bgc = 0.f, bgs = 0.f;

    int p0 = bx*K1PX + tid*4;
    float4 vy = *(const float4*)(xv_y + p0);
    float4 vx = *(const float4*)(xv_x + p0);
    float4 sy = *(const float4*)(xs_y + p0);
    float4 sx = *(const float4*)(xs_x + p0);
    float4 se = *(const float4*)(sdp + p0);
    int4   tt = *(const int4*)(tb + p0);
    #pragma unroll
    for (int j = 0; j < 4; ++j) {
        int pix = p0 + j;
        float ey = fast_tanh((&vy.x)[j]) + (float)(pix >> 10) * (1.0f/1024.0f);
        float ex = fast_tanh((&vx.x)[j]) + (float)(pix & 1023) * (1.0f/1024.0f);
        float gy = (&sy.x)[j], gx = (&sx.x)[j];
        int tv = (&tt.x)[j];
        if (tv == 0) {
            float s = fast_sigmoid((&se.x)[j]);
            bgc += 1.f; bgs += s*s;
        }
        float q = gy*gy + gx*gx;
        #pragma unroll
        for (int n = 0; n < NI; ++n) {
            float m = (tv == n+1) ? 1.0f : 0.0f;
            cnt[n] += m; sey[n] += m*ey; sex[n] += m*ex;
            sgy[n] += m*gy; sgx[n] += m*gx; sq[n] += m*q;
        }
    }
    __shared__ float sw[4*64];
    #define RED50(val, slot) { float r_ = wred(val); if (lane == 63) sw[wid*64 + (slot)] = r_; }
    #pragma unroll
    for (int n = 0; n < NI; ++n) {
        RED50(cnt[n], n*6+0); RED50(sey[n], n*6+1); RED50(sex[n], n*6+2);
        RED50(sgy[n], n*6+3); RED50(sgx[n], n*6+4); RED50(sq[n],  n*6+5);
    }
    RED50(bgc, 48); RED50(bgs, 49);
    #undef RED50
    __syncthreads();
    if (tid < 50) {
        float s = sw[tid] + sw[64+tid] + sw[128+tid] + sw[192+tid];
        pk1[(size_t)(b*K1B + bx)*64 + tid] = s;   // one coalesced 200B row per block
    }
}

// ---------------- K2: reduce partials + finalize params ----------------
__global__ __launch_bounds__(1024) void k2_finalize(float* __restrict__ wsf,
                                                    const float* __restrict__ pk1,
                                                    float* __restrict__ out) {
    const int tid = threadIdx.x;
    __shared__ float part[16*64];
    __shared__ float ssum[4*64];
    const int v = tid & 63, g = tid >> 6;    // g = 0..15
    const int b = g >> 2, c = g & 3;
    float acc = 0.f;
    const int jbase = b*K1B + c*128;
    #pragma unroll 8
    for (int i = 0; i < 128; ++i) acc += pk1[(size_t)(jbase + i)*64 + v];  // coalesced
    part[g*64 + v] = acc;
    __syncthreads();
    if (tid < 256) {
        int vb = tid & 63, bb = tid >> 6;
        ssum[bb*64+vb] = part[(bb*4+0)*64+vb] + part[(bb*4+1)*64+vb]
                       + part[(bb*4+2)*64+vb] + part[(bb*4+3)*64+vb];
    }
    __syncthreads();
    if (tid < NSEG) {
        int n = tid >> 2, bb = tid & 3;      // seg = n*B + bb = tid
        float cv  = ssum[bb*64 + n*6+0];
        float sey = ssum[bb*64 + n*6+1];
        float sex = ssum[bb*64 + n*6+2];
        float sgy = ssum[bb*64 + n*6+3];
        float sgx = ssum[bb*64 + n*6+4];
        float sq  = ssum[bb*64 + n*6+5];
        float safe = fmaxf(cv, 1.0f);
        float ipy = sgy/safe, ipx = sgx/safe;
        wsf[D_CENY+tid] = sey/safe;
        wsf[D_CENX+tid] = sex/safe;
        wsf[D_PSY+tid]  = expf(10.0f*ipy);
        wsf[D_PSX+tid]  = expf(10.0f*ipx);
        wsf[D_CNT+tid]  = cv;
        wsf[D_SL+tid]   = sq/safe - (ipy*ipy + ipx*ipx);
    } else if (tid < NSEG + B) {
        int bb = tid - NSEG;
        wsf[D_BGL+bb] = ssum[bb*64+49] / fmaxf(ssum[bb*64+48], 1.0f);
    } else if (tid == 40) {
        out[0] = 0.f;
    }
}

// ---------------- K3: LDS histograms, key-0 skipped ----------------
__global__ __launch_bounds__(512) void k3_hist(const float* __restrict__ xv,
                                               const float* __restrict__ xseed,
                                               const int*  __restrict__ t,
                                               const float* __restrict__ wsf,
                                               unsigned* __restrict__ hist_g,
                                               float* __restrict__ fgp) {
    const int strip = blockIdx.x;
    const int b     = blockIdx.y;
    const int tid   = threadIdx.x;
    const int lane  = tid & 63;

    __shared__ unsigned hist[NI*NB];   // 32 KB: pos<<16 | neg
    for (int i = tid; i < NI*NB; i += 512) hist[i] = 0u;
    __shared__ float spar[4*NI];
    if (tid < 4*NI) {
        int n = tid & (NI-1), q = tid >> 3;
        spar[tid] = wsf[q*32 + n*B + b];   // q: 0=ceny 1=cenx 2=psy 3=psx
    }
    __syncthreads();

    float ceny[NI], cenx[NI], psy[NI], psx[NI], fgn[NI];
    #pragma unroll
    for (int n = 0; n < NI; ++n) {
        ceny[n] = spar[n]; cenx[n] = spar[NI+n];
        psy[n] = spar[2*NI+n]; psx[n] = spar[3*NI+n];
        fgn[n] = 0.f;
    }

    const float* xv_y = xv + (size_t)b*2*P;
    const float* xv_x = xv_y + P;
    const float* sdp  = xseed + (size_t)b*P;
    const int*   tb   = t + (size_t)b*P;
    const int base = strip * STRIP_PX;

    #pragma unroll
    for (int it = 0; it < STRIP_PX/2048; ++it) {   // 2 iters
        int p0 = base + it*2048 + tid*4;
        float4 vy = *(const float4*)(xv_y + p0);
        float4 vx = *(const float4*)(xv_x + p0);
        float4 se = *(const float4*)(sdp + p0);
        int4   tt = *(const int4*)(tb + p0);
        #pragma unroll
        for (int j = 0; j < 4; ++j) {
            int pix = p0 + j;
            float ey = fast_tanh((&vy.x)[j]) + (float)(pix >> 10) * (1.0f/1024.0f);
            float ex = fast_tanh((&vx.x)[j]) + (float)(pix & 1023) * (1.0f/1024.0f);
            int tv = (&tt.x)[j];
            float gown = 0.f;
            #pragma unroll
            for (int n = 0; n < NI; ++n) {
                float dy = ey - ceny[n], dx = ex - cenx[n];
                float g = __expf(-0.5f * (psy[n]*dy*dy + psx[n]*dx*dx));
                bool lab = (tv == n+1);
                float err = lab ? (2.0f - 2.0f*g) : (2.0f*g);
                int key = (int)(err * INV_BW);
                key = key > (NB-1) ? (NB-1) : key;
                // key==0 counts are reconstructed exactly in K4 from totals
                if (key > 0) atomicAdd(&hist[n*NB + key], lab ? 0x10000u : 1u);
                if (lab) gown = g;
            }
            if (tv > 0) {
                float s = fast_sigmoid((&se.x)[j]);
                float d = s - gown;
                float dd = d*d;
                #pragma unroll
                for (int n = 0; n < NI; ++n) fgn[n] += (tv == n+1) ? dd : 0.f;
            }
        }
    }
    __syncthreads();
    for (int i = tid; i < NI*NB; i += 512) {
        int n = i >> 10, key = i & (NB-1);
        int seg = n*B + b;
        hist_g[((size_t)(seg*NSTRIP + strip))*NB + key] = hist[i];
    }
    __shared__ float sfg[NI];
    if (tid < NI) sfg[tid] = 0.f;
    __syncthreads();
    #pragma unroll
    for (int n = 0; n < NI; ++n) {
        float r = wred(fgn[n]);
        if (lane == 63 && r != 0.f) atomicAdd(&sfg[n], r);   // LDS, 8-way max
    }
    __syncthreads();
    if (tid < NI) fgp[tid*512 + b*NSTRIP + strip] = sfg[tid];  // plain store
}

// ---------------- K4: fold + suffix scan + finalize (fused) ----------------
__global__ __launch_bounds__(256) void k4_final(const unsigned* __restrict__ hist_g,
                                                const float* __restrict__ wsf,
                                                const float* __restrict__ fgp,
                                                float* __restrict__ out) {
    const int seg = blockIdx.x, tid = threadIdx.x;
    const int n = seg >> 2, b = seg & 3;
    __shared__ float scnt[NSEG];
    if (tid < NSEG) scnt[tid] = wsf[D_CNT + tid];
    __syncthreads();

    if (seg == 0 && tid == 0) {   // sigma loss + background seed loss
        float add = 0.f;
        for (int bb = 0; bb < B; ++bb) {
            int np = 0; float ss = 0.f;
            for (int k = 0; k < NI; ++k) {
                float c = scnt[k*4 + bb];
                if (c > 0.5f) { np++; ss += wsf[D_SL + k*4 + bb]; }
            }
            float npf = fmaxf((float)np, 1.0f);
            add += ss/npf + wsf[D_BGL+bb] / (1.0f + (float)np);
        }
        atomicAdd(out, add * (1.0f/(float)B));
    }

    const float G = scnt[seg];
    if (G < 0.5f) return;   // uniform across block
    int npc = 0;
    #pragma unroll
    for (int k = 0; k < NI; ++k) npc += (scnt[k*4 + b] > 0.5f) ? 1 : 0;

    // fg seed partial reduce (128 strips)
    __shared__ float sfr[128];
    if (tid < 128) sfr[tid] = fgp[n*512 + b*NSTRIP + tid];
    __syncthreads();
    #pragma unroll
    for (int d = 64; d > 0; d >>= 1) {
        if (tid < d) sfr[tid] += sfr[tid + d];
        __syncthreads();
    }
    const float FG = sfr[0];

    // fold 128 strip histograms: thread t owns keys 4t..4t+3
    unsigned pos4[4] = {0u,0u,0u,0u}, neg4[4] = {0u,0u,0u,0u};
    const uint4* hp = (const uint4*)(hist_g + (size_t)seg*NSTRIP*NB) + tid;
    #pragma unroll 8
    for (int s = 0; s < NSTRIP; ++s) {
        uint4 v = hp[(size_t)s*(NB/4)];
        pos4[0] += v.x >> 16; neg4[0] += v.x & 0xffffu;
        pos4[1] += v.y >> 16; neg4[1] += v.y & 0xffffu;
        pos4[2] += v.z >> 16; neg4[2] += v.z & 0xffffu;
        pos4[3] += v.w >> 16; neg4[3] += v.w & 0xffffu;
    }
    unsigned tp = pos4[0]+pos4[1]+pos4[2]+pos4[3];
    unsigned tn = neg4[0]+neg4[1]+neg4[2]+neg4[3];

    // suffix (descending-key) inclusive scan over thread totals
    __shared__ unsigned up[256], un[256];
    up[tid] = tp; un[tid] = tn;
    __syncthreads();
    for (int d = 1; d < 256; d <<= 1) {
        unsigned ap = (tid + d < 256) ? up[tid + d] : 0u;
        unsigned an = (tid + d < 256) ? un[tid + d] : 0u;
        __syncthreads();
        up[tid] += ap; un[tid] += an;
        __syncthreads();
    }
    const unsigned TP = up[0], TN = un[0];
    const unsigned Gu = (unsigned)(G + 0.5f);
    const unsigned NEGu = (unsigned)P - Gu;
    unsigned cump = up[tid] - tp;   // counts with key strictly greater
    unsigned cumn = un[tid] - tn;

    const double dG = (double)G;
    double acc = 0.0;
    #pragma unroll
    for (int j = 3; j >= 0; --j) {
        unsigned cp = pos4[j], cn = neg4[j];
        int key = tid*4 + j;
        if (tid == 0 && j == 0) { cp = Gu - TP; cn = NEGu - TN; }  // exact bucket-0
        if (cp | cn) {
            unsigned ep = cump, en = cumn;
            unsigned epi = ep + cp, eni = en + cn;
            double jb = 1.0 - (dG - (double)ep)  / (dG + (double)en);
            double ja = 1.0 - (dG - (double)epi) / (dG + (double)eni);
            acc += (((double)key + 0.5) * (2.0/(double)NB)) * (ja - jb);
        }
        cump += cp; cumn += cn;
    }
    __shared__ double sdd[256];
    sdd[tid] = acc;
    __syncthreads();
    #pragma unroll
    for (int d = 128; d > 0; d >>= 1) {
        if (tid < d) sdd[tid] += sdd[tid + d];
        __syncthreads();
    }
    if (tid == 0) {
        float npf = fmaxf((float)npc, 1.0f);
        float val = (float)sdd[0] / (npf * (float)B)
                  + (FG / G) / ((1.0f + (float)npc) * (float)B);
        atomicAdd(out, val);
    }
}

extern "C" void kernel_launch(void* const* d_in, const int* in_sizes, int n_in,
                              void* d_out, int out_size, void* d_ws, size_t ws_size,
                              hipStream_t stream) {
    (void)in_sizes; (void)n_in; (void)out_size; (void)ws_size;
    const float* xv  = (const float*)d_in[0];
    const float* xs  = (const float*)d_in[1];
    const float* xsd = (const float*)d_in[2];
    const int*   t   = (const int*)d_in[3];
    float* wsf = (float*)d_ws;
    unsigned* hist_g = (unsigned*)d_ws + OFF_HIST;
    float* pk1 = wsf + OFF_PK1;
    float* fgp = wsf + OFF_FGP;
    float* out = (float*)d_out;

    k1_stats<<<dim3(K1B, B), 256, 0, stream>>>(xv, xs, xsd, t, pk1);
    k2_finalize<<<1, 1024, 0, stream>>>(wsf, pk1, out);
    k3_hist<<<dim3(NSTRIP, B), 512, 0, stream>>>(xv, xsd, t, wsf, hist_g, fgp);
    k4_final<<<NSEG, 256, 0, stream>>>(hist_g, wsf, fgp, out);
}

// Round 5
// 134.541 us; speedup vs baseline: 6.4680x; 1.0378x over previous
//
#include <hip/hip_runtime.h>
#include <math.h>

#define B 4
#define H 512
#define W 1024
#define P (H*W)            // 524288
#define NI 8
#define NSEG 32            // seg = n*B + b
#define NB 1024            // histogram buckets over err in [0,2]
#define INV_BW ((float)NB/2.0f)
#define NSTRIP 128
#define STRIP_PX (P/NSTRIP) // 4096
#define K1B 512             // k1 blocks per batch
#define K1PX (P/K1B)        // 1024 px per k1 block

// ---- ws layout (4-byte units) ----
#define D_CENY 0
#define D_CENX 32
#define D_PSY  64
#define D_PSX  96
#define D_CNT  128
#define D_SL   160
#define D_BGL  192          // 4
#define OFF_FGP 256         // NI*512 floats = 16 KB
#define OFF_HIST (256 + NI*512)              // u32: NSEG*NSTRIP*NB = 16 MB
#define OFF_FOLD (OFF_HIST + NSEG*NSTRIP*NB) // u32: 2*NSEG*NB = 256 KB
#define OFF_PK1  OFF_HIST   // pk1 (2048*64 floats = 512 KB) overlaps hist:
                            // k1 writes pk1 -> k2 consumes -> k3 overwrites hist. Safe.

__device__ __forceinline__ float fast_tanh(float x) {
    float e = __expf(2.0f * x);
    return 1.0f - 2.0f / (e + 1.0f);
}
__device__ __forceinline__ float fast_sigmoid(float x) {
    return 1.0f / (1.0f + __expf(-x));
}

// DPP wave64 sum-reduction (rocPRIM sequence): total lands in lane 63.
template<int CTRL, int RM>
__device__ __forceinline__ float dpp_add(float x) {
    int y = __builtin_amdgcn_update_dpp(0, __float_as_int(x), CTRL, RM, 0xF, true);
    return x + __int_as_float(y);
}
__device__ __forceinline__ float wred(float x) {
    x = dpp_add<0x111, 0xF>(x);   // row_shr:1
    x = dpp_add<0x112, 0xF>(x);   // row_shr:2
    x = dpp_add<0x114, 0xF>(x);   // row_shr:4
    x = dpp_add<0x118, 0xF>(x);   // row_shr:8
    x = dpp_add<0x142, 0xA>(x);   // row_bcast:15 -> rows 1,3
    x = dpp_add<0x143, 0xC>(x);   // row_bcast:31 -> rows 2,3
    return x;                     // lane 63 = wave total
}

// ---------------- K1: per-block partial sums (no global atomics) ----------------
__global__ __launch_bounds__(256) void k1_stats(const float* __restrict__ xv,
                                                const float* __restrict__ xs,
                                                const float* __restrict__ xseed,
                                                const int*  __restrict__ t,
                                                float* __restrict__ pk1) {
    const int b = blockIdx.y, bx = blockIdx.x, tid = threadIdx.x;
    const int lane = tid & 63, wid = tid >> 6;
    const float* xv_y = xv + (size_t)b*2*P;
    const float* xv_x = xv_y + P;
    const float* xs_y = xs + (size_t)b*2*P;
    const float* xs_x = xs_y + P;
    const float* sdp  = xseed + (size_t)b*P;
    const int*   tb   = t + (size_t)b*P;

    float cnt[NI], sey[NI], sex[NI], sgy[NI], sgx[NI], sq[NI];
    #pragma unroll
    for (int n = 0; n < NI; ++n) { cnt[n]=0.f; sey[n]=0.f; sex[n]=0.f; sgy[n]=0.f; sgx[n]=0.f; sq[n]=0.f; }
    float bgc = 0.f, bgs = 0.f;

    int p0 = bx*K1PX + tid*4;
    float4 vy = *(const float4*)(xv_y + p0);
    float4 vx = *(const float4*)(xv_x + p0);
    float4 sy = *(const float4*)(xs_y + p0);
    float4 sx = *(const float4*)(xs_x + p0);
    float4 se = *(const float4*)(sdp + p0);
    int4   tt = *(const int4*)(tb + p0);
    #pragma unroll
    for (int j = 0; j < 4; ++j) {
        int pix = p0 + j;
        float ey = fast_tanh((&vy.x)[j]) + (float)(pix >> 10) * (1.0f/1024.0f);
        float ex = fast_tanh((&vx.x)[j]) + (float)(pix & 1023) * (1.0f/1024.0f);
        float gy = (&sy.x)[j], gx = (&sx.x)[j];
        int tv = (&tt.x)[j];
        if (tv == 0) {
            float s = fast_sigmoid((&se.x)[j]);
            bgc += 1.f; bgs += s*s;
        }
        float q = gy*gy + gx*gx;
        #pragma unroll
        for (int n = 0; n < NI; ++n) {
            float m = (tv == n+1) ? 1.0f : 0.0f;
            cnt[n] += m; sey[n] += m*ey; sex[n] += m*ex;
            sgy[n] += m*gy; sgx[n] += m*gx; sq[n] += m*q;
        }
    }
    __shared__ float sw[4*64];
    #define RED50(val, slot) { float r_ = wred(val); if (lane == 63) sw[wid*64 + (slot)] = r_; }
    #pragma unroll
    for (int n = 0; n < NI; ++n) {
        RED50(cnt[n], n*6+0); RED50(sey[n], n*6+1); RED50(sex[n], n*6+2);
        RED50(sgy[n], n*6+3); RED50(sgx[n], n*6+4); RED50(sq[n],  n*6+5);
    }
    RED50(bgc, 48); RED50(bgs, 49);
    #undef RED50
    __syncthreads();
    if (tid < 50) {
        float s = sw[tid] + sw[64+tid] + sw[128+tid] + sw[192+tid];
        pk1[(size_t)(b*K1B + bx)*64 + tid] = s;   // one coalesced 200B row per block
    }
}

// ---------------- K2: reduce partials + finalize params ----------------
__global__ __launch_bounds__(1024) void k2_finalize(float* __restrict__ wsf,
                                                    const float* __restrict__ pk1,
                                                    float* __restrict__ out) {
    const int tid = threadIdx.x;
    __shared__ float part[16*64];
    __shared__ float ssum[4*64];
    const int v = tid & 63, g = tid >> 6;    // g = 0..15
    const int b = g >> 2, c = g & 3;
    float acc = 0.f;
    const int jbase = b*K1B + c*128;
    #pragma unroll 8
    for (int i = 0; i < 128; ++i) acc += pk1[(size_t)(jbase + i)*64 + v];  // coalesced
    part[g*64 + v] = acc;
    __syncthreads();
    if (tid < 256) {
        int vb = tid & 63, bb = tid >> 6;
        ssum[bb*64+vb] = part[(bb*4+0)*64+vb] + part[(bb*4+1)*64+vb]
                       + part[(bb*4+2)*64+vb] + part[(bb*4+3)*64+vb];
    }
    __syncthreads();
    if (tid < NSEG) {
        int n = tid >> 2, bb = tid & 3;      // seg = n*B + bb = tid
        float cv  = ssum[bb*64 + n*6+0];
        float sey = ssum[bb*64 + n*6+1];
        float sex = ssum[bb*64 + n*6+2];
        float sgy = ssum[bb*64 + n*6+3];
        float sgx = ssum[bb*64 + n*6+4];
        float sq  = ssum[bb*64 + n*6+5];
        float safe = fmaxf(cv, 1.0f);
        float ipy = sgy/safe, ipx = sgx/safe;
        wsf[D_CENY+tid] = sey/safe;
        wsf[D_CENX+tid] = sex/safe;
        wsf[D_PSY+tid]  = expf(10.0f*ipy);
        wsf[D_PSX+tid]  = expf(10.0f*ipx);
        wsf[D_CNT+tid]  = cv;
        wsf[D_SL+tid]   = sq/safe - (ipy*ipy + ipx*ipx);
    } else if (tid < NSEG + B) {
        int bb = tid - NSEG;
        wsf[D_BGL+bb] = ssum[bb*64+49] / fmaxf(ssum[bb*64+48], 1.0f);
    } else if (tid == 40) {
        out[0] = 0.f;
    }
}

// ---------------- K3: LDS histograms, key-0 skipped ----------------
__global__ __launch_bounds__(512) void k3_hist(const float* __restrict__ xv,
                                               const float* __restrict__ xseed,
                                               const int*  __restrict__ t,
                                               const float* __restrict__ wsf,
                                               unsigned* __restrict__ hist_g,
                                               float* __restrict__ fgp) {
    const int strip = blockIdx.x;
    const int b     = blockIdx.y;
    const int tid   = threadIdx.x;
    const int lane  = tid & 63;

    __shared__ unsigned hist[NI*NB];   // 32 KB: pos<<16 | neg
    for (int i = tid; i < NI*NB; i += 512) hist[i] = 0u;
    __shared__ float spar[4*NI];
    if (tid < 4*NI) {
        int n = tid & (NI-1), q = tid >> 3;
        spar[tid] = wsf[q*32 + n*B + b];   // q: 0=ceny 1=cenx 2=psy 3=psx
    }
    __syncthreads();

    float ceny[NI], cenx[NI], psy[NI], psx[NI], fgn[NI];
    #pragma unroll
    for (int n = 0; n < NI; ++n) {
        ceny[n] = spar[n]; cenx[n] = spar[NI+n];
        psy[n] = spar[2*NI+n]; psx[n] = spar[3*NI+n];
        fgn[n] = 0.f;
    }

    const float* xv_y = xv + (size_t)b*2*P;
    const float* xv_x = xv_y + P;
    const float* sdp  = xseed + (size_t)b*P;
    const int*   tb   = t + (size_t)b*P;
    const int base = strip * STRIP_PX;

    #pragma unroll
    for (int it = 0; it < STRIP_PX/2048; ++it) {   // 2 iters
        int p0 = base + it*2048 + tid*4;
        float4 vy = *(const float4*)(xv_y + p0);
        float4 vx = *(const float4*)(xv_x + p0);
        float4 se = *(const float4*)(sdp + p0);
        int4   tt = *(const int4*)(tb + p0);
        #pragma unroll
        for (int j = 0; j < 4; ++j) {
            int pix = p0 + j;
            float ey = fast_tanh((&vy.x)[j]) + (float)(pix >> 10) * (1.0f/1024.0f);
            float ex = fast_tanh((&vx.x)[j]) + (float)(pix & 1023) * (1.0f/1024.0f);
            int tv = (&tt.x)[j];
            float gown = 0.f;
            #pragma unroll
            for (int n = 0; n < NI; ++n) {
                float dy = ey - ceny[n], dx = ex - cenx[n];
                float g = __expf(-0.5f * (psy[n]*dy*dy + psx[n]*dx*dx));
                bool lab = (tv == n+1);
                float err = lab ? (2.0f - 2.0f*g) : (2.0f*g);
                int key = (int)(err * INV_BW);
                key = key > (NB-1) ? (NB-1) : key;
                // key==0 counts are reconstructed exactly in K4b from totals
                if (key > 0) atomicAdd(&hist[n*NB + key], lab ? 0x10000u : 1u);
                if (lab) gown = g;
            }
            if (tv > 0) {
                float s = fast_sigmoid((&se.x)[j]);
                float d = s - gown;
                float dd = d*d;
                #pragma unroll
                for (int n = 0; n < NI; ++n) fgn[n] += (tv == n+1) ? dd : 0.f;
            }
        }
    }
    __syncthreads();
    for (int i = tid; i < NI*NB; i += 512) {
        int n = i >> 10, key = i & (NB-1);
        int seg = n*B + b;
        hist_g[((size_t)(seg*NSTRIP + strip))*NB + key] = hist[i];
    }
    __shared__ float sfg[NI];
    if (tid < NI) sfg[tid] = 0.f;
    __syncthreads();
    #pragma unroll
    for (int n = 0; n < NI; ++n) {
        float r = wred(fgn[n]);
        if (lane == 63 && r != 0.f) atomicAdd(&sfg[n], r);   // LDS, 8-way max
    }
    __syncthreads();
    if (tid < NI) fgp[tid*512 + b*NSTRIP + strip] = sfg[tid];  // plain store
}

// ---------------- K4a: wide fold of strip histograms (128 blocks) ----------------
__global__ __launch_bounds__(256) void k4a_fold(const unsigned* __restrict__ hist_g,
                                                unsigned* __restrict__ fold) {
    const int seg = blockIdx.x >> 2;                 // NSEG*4 = 128 blocks
    const int key = (blockIdx.x & 3)*256 + threadIdx.x;
    const unsigned* src = hist_g + (size_t)seg*NSTRIP*NB + key;
    unsigned pos = 0u, neg = 0u;
    #pragma unroll 8
    for (int s = 0; s < NSTRIP; ++s) {
        unsigned v = src[(size_t)s*NB];              // coalesced across threads
        pos += v >> 16; neg += v & 0xffffu;
    }
    fold[(size_t)seg*NB + key] = pos;
    fold[(size_t)(NSEG + seg)*NB + key] = neg;
}

// ---------------- K4b: suffix scan + finalize ----------------
__global__ __launch_bounds__(256) void k4b_scan(const unsigned* __restrict__ fold,
                                                const float* __restrict__ wsf,
                                                const float* __restrict__ fgp,
                                                float* __restrict__ out) {
    const int seg = blockIdx.x, tid = threadIdx.x;
    const int n = seg >> 2, b = seg & 3;
    __shared__ float scnt[NSEG];
    if (tid < NSEG) scnt[tid] = wsf[D_CNT + tid];
    __syncthreads();

    if (seg == 0 && tid == 0) {   // sigma loss + background seed loss
        float add = 0.f;
        for (int bb = 0; bb < B; ++bb) {
            int np = 0; float ss = 0.f;
            for (int k = 0; k < NI; ++k) {
                float c = scnt[k*4 + bb];
                if (c > 0.5f) { np++; ss += wsf[D_SL + k*4 + bb]; }
            }
            float npf = fmaxf((float)np, 1.0f);
            add += ss/npf + wsf[D_BGL+bb] / (1.0f + (float)np);
        }
        atomicAdd(out, add * (1.0f/(float)B));
    }

    const float G = scnt[seg];
    if (G < 0.5f) return;   // uniform across block
    int npc = 0;
    #pragma unroll
    for (int k = 0; k < NI; ++k) npc += (scnt[k*4 + b] > 0.5f) ? 1 : 0;

    // fg seed partial reduce (128 strips)
    __shared__ float sfr[128];
    if (tid < 128) sfr[tid] = fgp[n*512 + b*NSTRIP + tid];
    __syncthreads();
    #pragma unroll
    for (int d = 64; d > 0; d >>= 1) {
        if (tid < d) sfr[tid] += sfr[tid + d];
        __syncthreads();
    }
    const float FG = sfr[0];

    // thread t owns keys 4t..4t+3 from the folded arrays
    uint4 pv = *((const uint4*)(fold + (size_t)seg*NB) + tid);
    uint4 nv = *((const uint4*)(fold + (size_t)(NSEG + seg)*NB) + tid);
    unsigned pos4[4] = {pv.x, pv.y, pv.z, pv.w};
    unsigned neg4[4] = {nv.x, nv.y, nv.z, nv.w};
    unsigned tp = pos4[0]+pos4[1]+pos4[2]+pos4[3];
    unsigned tn = neg4[0]+neg4[1]+neg4[2]+neg4[3];

    // suffix (descending-key) inclusive scan over thread totals
    __shared__ unsigned up[256], un[256];
    up[tid] = tp; un[tid] = tn;
    __syncthreads();
    for (int d = 1; d < 256; d <<= 1) {
        unsigned ap = (tid + d < 256) ? up[tid + d] : 0u;
        unsigned an = (tid + d < 256) ? un[tid + d] : 0u;
        __syncthreads();
        up[tid] += ap; un[tid] += an;
        __syncthreads();
    }
    const unsigned TP = up[0], TN = un[0];
    const unsigned Gu = (unsigned)(G + 0.5f);
    const unsigned NEGu = (unsigned)P - Gu;
    unsigned cump = up[tid] - tp;   // counts with key strictly greater
    unsigned cumn = un[tid] - tn;

    const double dG = (double)G;
    double acc = 0.0;
    #pragma unroll
    for (int j = 3; j >= 0; --j) {
        unsigned cp = pos4[j], cn = neg4[j];
        int key = tid*4 + j;
        if (tid == 0 && j == 0) { cp = Gu - TP; cn = NEGu - TN; }  // exact bucket-0
        if (cp | cn) {
            unsigned ep = cump, en = cumn;
            unsigned epi = ep + cp, eni = en + cn;
            double jb = 1.0 - (dG - (double)ep)  / (dG + (double)en);
            double ja = 1.0 - (dG - (double)epi) / (dG + (double)eni);
            acc += (((double)key + 0.5) * (2.0/(double)NB)) * (ja - jb);
        }
        cump += cp; cumn += cn;
    }
    __shared__ double sdd[256];
    sdd[tid] = acc;
    __syncthreads();
    #pragma unroll
    for (int d = 128; d > 0; d >>= 1) {
        if (tid < d) sdd[tid] += sdd[tid + d];
        __syncthreads();
    }
    if (tid == 0) {
        float npf = fmaxf((float)npc, 1.0f);
        float val = (float)sdd[0] / (npf * (float)B)
                  + (FG / G) / ((1.0f + (float)npc) * (float)B);
        atomicAdd(out, val);
    }
}

extern "C" void kernel_launch(void* const* d_in, const int* in_sizes, int n_in,
                              void* d_out, int out_size, void* d_ws, size_t ws_size,
                              hipStream_t stream) {
    (void)in_sizes; (void)n_in; (void)out_size; (void)ws_size;
    const float* xv  = (const float*)d_in[0];
    const float* xs  = (const float*)d_in[1];
    const float* xsd = (const float*)d_in[2];
    const int*   t   = (const int*)d_in[3];
    float* wsf = (float*)d_ws;
    unsigned* hist_g = (unsigned*)d_ws + OFF_HIST;
    unsigned* fold   = (unsigned*)d_ws + OFF_FOLD;
    float* pk1 = wsf + OFF_PK1;
    float* fgp = wsf + OFF_FGP;
    float* out = (float*)d_out;

    k1_stats<<<dim3(K1B, B), 256, 0, stream>>>(xv, xs, xsd, t, pk1);
    k2_finalize<<<1, 1024, 0, stream>>>(wsf, pk1, out);
    k3_hist<<<dim3(NSTRIP, B), 512, 0, stream>>>(xv, xsd, t, wsf, hist_g, fgp);
    k4a_fold<<<NSEG*4, 256, 0, stream>>>(hist_g, fold);
    k4b_scan<<<NSEG, 256, 0, stream>>>(fold, wsf, fgp, out);
}